// Round 6
// baseline (12026.988 us; speedup 1.0000x reference)
//
#include <hip/hip_runtime.h>
#include <stdint.h>

// Problem sizes (fixed)
#define BATCH 256
#define HDIM  256
#define MDIM  128
#define NSTEPS 512

// ---------------------------------------------------------------------------
__global__ __launch_bounds__(256) void k_zero(float* __restrict__ p, int n) {
    int i = blockIdx.x * 256 + threadIdx.x;
    if (i < n) p[i] = 0.f;
}

// ---------------------------------------------------------------------------
// f32 tiled GEMM: out[M][N] = act(A[M][K] @ W[N][K]^T + b)
// block (16,16), grid (M/16, N/16)
// ---------------------------------------------------------------------------
template <int RELU>
__global__ __launch_bounds__(256) void k_gemm_f32(
    const float* __restrict__ A, const float* __restrict__ W,
    const float* __restrict__ bvec, float* __restrict__ out, int N, int K) {
    __shared__ float At[16][17];
    __shared__ float Wt[16][17];
    int tx = threadIdx.x, ty = threadIdx.y;
    int mrow = blockIdx.x * 16 + ty;
    int nrow = blockIdx.y * 16 + ty;
    float acc = 0.0f;
    for (int k0 = 0; k0 < K; k0 += 16) {
        At[ty][tx] = A[(size_t)mrow * K + k0 + tx];
        Wt[ty][tx] = W[(size_t)nrow * K + k0 + tx];
        __syncthreads();
#pragma unroll
        for (int kk = 0; kk < 16; ++kk) acc += At[ty][kk] * Wt[tx][kk];
        __syncthreads();
    }
    int n = blockIdx.y * 16 + tx;
    float r = acc + bvec[n];
    if (RELU) r = fmaxf(r, 0.0f);
    out[(size_t)mrow * N + n] = r;
}

// ---------------------------------------------------------------------------
// Literal GRU cell step: h_next = cell(x, h), torch math, gates (r,z,n).
//   gi = x @ w_ih^T + b_ih ; gh = h @ w_hh^T + b_hh
//   r = sigm(i_r+h_r); z = sigm(i_z+h_z); n = tanh(i_n + r*h_n)
//   h' = (1-z)*n + z*h
// grid (16 batch-tiles, 16 col-tiles), block 256 (r=tid&15, c=tid>>4).
// If PROJ: out1[:, t, :] = f32( hprev @ ow^T + ob ), cols j<128 (jt<8).
// ---------------------------------------------------------------------------
template <int PROJ>
__global__ __launch_bounds__(256) void k_stepL(
    const float* __restrict__ w_ih, const float* __restrict__ w_hh,
    const float* __restrict__ b_ih, const float* __restrict__ b_hh,
    const float* __restrict__ ow,   const float* __restrict__ obv,
    const float* __restrict__ xprev, const float* __restrict__ hprev,
    float* __restrict__ hnext, float* __restrict__ out1, int t) {
    __shared__ float xs[16][HDIM];
    __shared__ float hs[16][HDIM];
    int bt = blockIdx.x, jt = blockIdx.y, tid = threadIdx.x;
    for (int i = tid; i < 16 * HDIM; i += 256) {
        ((float*)xs)[i] = xprev[bt * 16 * HDIM + i];
        ((float*)hs)[i] = hprev[bt * 16 * HDIM + i];
    }
    __syncthreads();

    int r = tid & 15;   // batch row in tile
    int c = tid >> 4;   // col in tile
    int b = bt * 16 + r;
    int j = jt * 16 + c;
    const float* xrow = xs[r];
    const float* hrow = hs[r];
    const float* wi_r = w_ih + (size_t)j * HDIM;
    const float* wi_z = w_ih + (size_t)(256 + j) * HDIM;
    const float* wi_n = w_ih + (size_t)(512 + j) * HDIM;
    const float* wh_r = w_hh + (size_t)j * HDIM;
    const float* wh_z = w_hh + (size_t)(256 + j) * HDIM;
    const float* wh_n = w_hh + (size_t)(512 + j) * HDIM;

    float ir = 0.f, iz = 0.f, in_ = 0.f, hr = 0.f, hz = 0.f, hn = 0.f;
#pragma unroll 4
    for (int k = 0; k < HDIM; ++k) {
        float xk = xrow[k], hk = hrow[k];
        ir  += xk * wi_r[k];  iz += xk * wi_z[k];  in_ += xk * wi_n[k];
        hr  += hk * wh_r[k];  hz += hk * wh_z[k];  hn  += hk * wh_n[k];
    }
    float rr = 1.f / (1.f + expf(-((ir + b_ih[j])       + (hr + b_hh[j]))));
    float zz = 1.f / (1.f + expf(-((iz + b_ih[256 + j]) + (hz + b_hh[256 + j]))));
    float nn = tanhf((in_ + b_ih[512 + j]) + rr * (hn + b_hh[512 + j]));
    float hv = (1.f - zz) * nn + zz * hrow[j];
    hnext[(size_t)b * HDIM + j] = hv;

    if (PROJ && jt < 8) {
        const float* owr = ow + (size_t)j * HDIM;
        float ao = 0.f;
#pragma unroll 4
        for (int k = 0; k < HDIM; ++k) ao += hrow[k] * owr[k];
        out1[(size_t)b * (NSTEPS * MDIM) + (size_t)t * MDIM + j] = ao + obv[j];
    }
}

// ---------------------------------------------------------------------------
// Final: out1[:,511,:] = proj(h_512); out2 = h_512.  (both f32)
// ---------------------------------------------------------------------------
__global__ __launch_bounds__(256) void k_final(
    const float* __restrict__ ow, const float* __restrict__ obv,
    const float* __restrict__ h512, float* __restrict__ out1,
    float* __restrict__ out2) {
    __shared__ float hs[16][HDIM];
    int bt = blockIdx.x, jt = blockIdx.y, tid = threadIdx.x;
    for (int i = tid; i < 16 * HDIM; i += 256)
        ((float*)hs)[i] = h512[bt * 16 * HDIM + i];
    __syncthreads();
    int r = tid & 15, c = tid >> 4;
    int b = bt * 16 + r;
    int j = jt * 16 + c;
    if (jt < 8) {
        const float* owr = ow + (size_t)j * HDIM;
        float ao = 0.f;
#pragma unroll 4
        for (int k = 0; k < HDIM; ++k) ao += hs[r][k] * owr[k];
        out1[(size_t)b * (NSTEPS * MDIM) + 511ull * MDIM + j] = ao + obv[j];
    }
    out2[(size_t)b * HDIM + j] = hs[r][j];
}

// ---------------------------------------------------------------------------
extern "C" void kernel_launch(void* const* d_in, const int* in_sizes, int n_in,
                              void* d_out, int out_size, void* d_ws, size_t ws_size,
                              hipStream_t stream) {
    const float* P[11];
    for (int i = 0; i < 11 && i < n_in; ++i) P[i] = (const float*)d_in[i];

    // Runtime input-order detection via element-count signature (insurance;
    // evidence so far says dict order).
    const float *emb, *w1, *b1, *w2, *b2, *w_ih, *b_ih, *w_hh, *b_hh, *ow, *obv;
    if (n_in > 1 && in_sizes[1] == 256) {            // alphabetical
        emb = P[0]; b1 = P[1]; b2 = P[2]; w1 = P[3]; w2 = P[4];
        b_hh = P[5]; b_ih = P[6]; w_hh = P[7]; w_ih = P[8];
        obv = P[9]; ow = P[10];
    } else if (n_in > 1 && in_sizes[1] == 32768) {   // reversed dict
        obv = P[0]; ow = P[1]; b_hh = P[2]; w_hh = P[3]; b_ih = P[4];
        w_ih = P[5]; b2 = P[6]; w2 = P[7]; b1 = P[8]; w1 = P[9]; emb = P[10];
    } else {                                         // dict order (documented)
        emb = P[0]; w1 = P[1]; b1 = P[2]; w2 = P[3]; b2 = P[4];
        w_ih = P[5]; b_ih = P[6]; w_hh = P[7]; b_hh = P[8];
        ow = P[9]; obv = P[10];
    }

    // OUTPUTS ARE FLOAT32 (reference returns f32; template doc: "else float*").
    float* out1 = (float*)d_out;                            // [256][512][128] f32
    float* out2 = out1 + (size_t)BATCH * NSTEPS * MDIM;     // [256][256] f32

    // ws layout (1.31 MB; f32 internal state)
    char* ws = (char*)d_ws;
    float* zeros = (float*)(ws + 0);          // 262144 B
    float* hx    = (float*)(ws + 262144);     // 262144 B
    float* hA    = (float*)(ws + 524288);     // 262144 B
    float* hB    = (float*)(ws + 786432);     // 262144 B
    float* mid   = (float*)(ws + 1048576);    // 262144 B

    k_zero<<<256, 256, 0, stream>>>(zeros, BATCH * HDIM);

    // FNN: hx = relu(emb@w1^T + b1) @ w2^T + b2
    k_gemm_f32<1><<<dim3(16, 16), dim3(16, 16), 0, stream>>>(emb, w1, b1, mid, 256, 256);
    k_gemm_f32<0><<<dim3(16, 16), dim3(16, 16), 0, stream>>>(mid, w2, b2, hx, 256, 256);

    // Step 0: h_1 = cell(x=0, h=hx); no projection yet.
    k_stepL<0><<<dim3(16, 16), 256, 0, stream>>>(
        w_ih, w_hh, b_ih, b_hh, ow, obv, zeros, hx, hA, out1, 0);

    // Steps i=1..511: h_{i+1} = cell(h_i, h_i); project ys[i-1] = h_i at t=i-1.
    for (int i = 1; i <= 511; ++i) {
        const float* hp = (i & 1) ? hA : hB;
        float*       hn = (i & 1) ? hB : hA;
        k_stepL<1><<<dim3(16, 16), 256, 0, stream>>>(
            w_ih, w_hh, b_ih, b_hh, ow, obv, hp, hp, hn, out1, i - 1);
    }
    // h_512 is in hB. Project t=511 + emit hx_final.
    k_final<<<dim3(16, 16), 256, 0, stream>>>(ow, obv, hB, out1, out2);
}